// Round 1
// baseline (77.843 us; speedup 1.0000x reference)
//
#include <hip/hip_runtime.h>
#include <hip/hip_bf16.h>

// Framing op: x [16, 1048576] f32 -> out [16, 2048, 2048] f32
// out[b, f, t] = (f*512 + t >= 1536) ? x[b, f*512 + t - 1536] : 0.0f
// N_FFT = 2048, HOP = 512, zero-prefix = 1536.
//
// One thread per float4 of output. All offsets (f*512, 1536) are multiples
// of 4, so every float4 is either entirely in the zero prefix or an aligned
// float4 load from x. Memory-bound; linear gid order gives coalesced writes
// and L2-friendly overlapping reads across consecutive frames.

#define B_DIM   16
#define T_LEN   1048576u
#define N_FFT   2048
#define HOP     512
#define PREFIX  1536
#define NFRAMES 2048

__global__ __launch_bounds__(256) void frame_kernel(
    const float* __restrict__ x, float4* __restrict__ out)
{
    unsigned int gid = blockIdx.x * blockDim.x + threadIdx.x;
    // total float4 elems = 16 * 2048 * 2048 / 4 = 16,777,216 = 2^24
    unsigned int t4 = gid & 511u;            // float4 index within frame (512 per frame)
    unsigned int f  = (gid >> 9) & 2047u;    // frame index
    unsigned int b  = gid >> 20;             // batch index

    int i = (int)(f * HOP + t4 * 4u);        // position within padded signal xc
    float4 v;
    if (i >= PREFIX) {
        v = *reinterpret_cast<const float4*>(
                x + (size_t)b * T_LEN + (unsigned)(i - PREFIX));
    } else {
        v = make_float4(0.f, 0.f, 0.f, 0.f);
    }
    out[gid] = v;
}

extern "C" void kernel_launch(void* const* d_in, const int* in_sizes, int n_in,
                              void* d_out, int out_size, void* d_ws, size_t ws_size,
                              hipStream_t stream) {
    const float* x = (const float*)d_in[0];
    float4* out = (float4*)d_out;
    // out_size = 16*2048*2048 = 67,108,864 floats -> 16,777,216 float4s
    const unsigned int n4 = 16u * 2048u * 2048u / 4u;
    dim3 block(256);
    dim3 grid(n4 / 256u);  // 65536 blocks
    frame_kernel<<<grid, block, 0, stream>>>(x, out);
}

// Round 2
// 66.047 us; speedup vs baseline: 1.1786x; 1.1786x over previous
//
#include <hip/hip_runtime.h>
#include <hip/hip_bf16.h>

// Framing op: x [16, 1048576] f32 -> out [16, 2048, 2048] f32
// out[b, f, t] = (f*512 + t >= 1536) ? x[b, f*512 + t - 1536] : 0.0f
//
// SCATTER formulation: input element i = q*512 + r appears in exactly the
// 4 frames f = q+k (k=0..3) at position t = r + (3-k)*512 (when 0<=f<2048).
// One thread loads one float4 of x ONCE (compulsory 64 MiB read) and does
// 4 coalesced float4 stores (256 MiB write). The zero prefix (out positions
// with f*512+t < 1536) is covered by virtual slices q = -3..-1 writing zeros.
// Every output element is written exactly once -> deterministic, no atomics.
//
// Traffic: 64 MiB read + 256 MiB write = 335 MB, independent of cache
// behavior (the previous gather re-read x 4x because overlapping frames
// land on different XCD L2s).

#define T4_PER_B   262144u   // 1048576 / 4 float4 per batch
#define R4         128u      // float4 per 512-float slice
#define QI_COUNT   2051u     // q = -3 .. 2047
#define NFRAMES    2048u

__global__ __launch_bounds__(256) void scatter_frames(
    const float4* __restrict__ x4, float4* __restrict__ out4)
{
    unsigned int gid = blockIdx.x * blockDim.x + threadIdx.x;
    const unsigned int total = 16u * QI_COUNT * R4;   // 4,200,448
    if (gid >= total) return;

    unsigned int r4 = gid & (R4 - 1u);
    unsigned int rest = gid >> 7;
    unsigned int qi = rest % QI_COUNT;
    unsigned int b  = rest / QI_COUNT;
    int q = (int)qi - 3;

    float4 v;
    if (q >= 0) {
        v = x4[(size_t)b * T4_PER_B + (unsigned)q * R4 + r4];
    } else {
        v = make_float4(0.f, 0.f, 0.f, 0.f);
    }

    // frame f = q+k at float4-position r4 + (3-k)*128, for valid f
    size_t obase = ((size_t)b * NFRAMES) * 512u + r4;
#pragma unroll
    for (int k = 0; k < 4; ++k) {
        int f = q + k;
        if (f >= 0 && f < (int)NFRAMES) {
            out4[obase + (size_t)f * 512u + (unsigned)(3 - k) * 128u] = v;
        }
    }
}

extern "C" void kernel_launch(void* const* d_in, const int* in_sizes, int n_in,
                              void* d_out, int out_size, void* d_ws, size_t ws_size,
                              hipStream_t stream) {
    const float4* x4 = (const float4*)d_in[0];
    float4* out4 = (float4*)d_out;
    const unsigned int total = 16u * QI_COUNT * R4;
    dim3 block(256);
    dim3 grid((total + 255u) / 256u);  // 16408 blocks
    scatter_frames<<<grid, block, 0, stream>>>(x4, out4);
}